// Round 1
// baseline (16323.392 us; speedup 1.0000x reference)
//
#include <hip/hip_runtime.h>

#define N_NODES 50000
#define HID 128
#define NE 1600000
#define NH (N_NODES * HID)   // 6,400,000 floats per [N,HID] buffer

// ---------------------------------------------------------------------------
// SpMM: y[row] += val * x[col]  (COO, atomic scatter-add)
// One edge per 32 lanes; each lane does a float4 gather + 4 atomic adds.
// y must be pre-zeroed.
// ---------------------------------------------------------------------------
__global__ __launch_bounds__(256) void spmm_kernel(
    const int* __restrict__ rows, const int* __restrict__ cols,
    const float* __restrict__ vals, const float* __restrict__ x,
    float* __restrict__ y)
{
    int t   = blockIdx.x * 256 + threadIdx.x;
    int e   = t >> 5;
    int sub = t & 31;
    if (e >= NE) return;
    int   r = rows[e];
    int   c = cols[e];
    float v = vals[e];
    const float4 xv = ((const float4*)(x + (size_t)c * HID))[sub];
    float* yp = y + (size_t)r * HID + sub * 4;
    atomicAdd(yp + 0, v * xv.x);
    atomicAdd(yp + 1, v * xv.y);
    atomicAdd(yp + 2, v * xv.z);
    atomicAdd(yp + 3, v * xv.w);
}

// ---------------------------------------------------------------------------
// In-place abs over n float4's
// ---------------------------------------------------------------------------
__global__ __launch_bounds__(256) void abs_kernel(float* __restrict__ p, int n4)
{
    int i = blockIdx.x * 256 + threadIdx.x;
    if (i >= n4) return;
    float4 v = ((float4*)p)[i];
    v.x = fabsf(v.x); v.y = fabsf(v.y); v.z = fabsf(v.z); v.w = fabsf(v.w);
    ((float4*)p)[i] = v;
}

// ---------------------------------------------------------------------------
// Attention: e[n,b] = dot(relu(pair_b[n]), a); att = softmax over b (6)
// pair_b[n] = 256 contiguous floats:
//   n <  N/2 : X  + n*256          (branch-independent)
//   n >= N/2 : B_b + (2n-N)*128    (rows m, m+1 contiguous)
// One wave (64 lanes) per node, 4 floats per lane.
// ---------------------------------------------------------------------------
__global__ __launch_bounds__(256) void attn_kernel(
    const float* __restrict__ X, const float* __restrict__ B,
    const float* __restrict__ a, float* __restrict__ att)
{
    int wid  = (blockIdx.x * 256 + threadIdx.x) >> 6;
    int lane = threadIdx.x & 63;
    if (wid >= N_NODES) return;

    const float4 av = ((const float4*)a)[lane];
    float e[6];

    if (wid < N_NODES / 2) {
        const float4 p = ((const float4*)(X + (size_t)wid * 256))[lane];
        float s = fmaxf(p.x, 0.f) * av.x + fmaxf(p.y, 0.f) * av.y +
                  fmaxf(p.z, 0.f) * av.z + fmaxf(p.w, 0.f) * av.w;
        #pragma unroll
        for (int m = 1; m < 64; m <<= 1) s += __shfl_xor(s, m);
        #pragma unroll
        for (int b = 0; b < 6; ++b) e[b] = s;
    } else {
        int m = 2 * wid - N_NODES;
        #pragma unroll
        for (int b = 0; b < 6; ++b) {
            const float4 p =
                ((const float4*)(B + (size_t)b * NH + (size_t)m * HID))[lane];
            float s = fmaxf(p.x, 0.f) * av.x + fmaxf(p.y, 0.f) * av.y +
                      fmaxf(p.z, 0.f) * av.z + fmaxf(p.w, 0.f) * av.w;
            #pragma unroll
            for (int k = 1; k < 64; k <<= 1) s += __shfl_xor(s, k);
            e[b] = s;
        }
    }

    if (lane == 0) {
        float mx = e[0];
        #pragma unroll
        for (int b = 1; b < 6; ++b) mx = fmaxf(mx, e[b]);
        float ex[6], sum = 0.f;
        #pragma unroll
        for (int b = 0; b < 6; ++b) { ex[b] = expf(e[b] - mx); sum += ex[b]; }
        float inv = 1.f / sum;
        #pragma unroll
        for (int b = 0; b < 6; ++b) att[(size_t)wid * 6 + b] = ex[b] * inv;
    }
}

// ---------------------------------------------------------------------------
// h_prime[n,q] = (1/6) * sum_p att[n,p] * B_{(p*128+q)%6}[n, (p*128+q)/6]
// (torch-faithful scrambled reshape)
// ---------------------------------------------------------------------------
__global__ __launch_bounds__(256) void hprime_kernel(
    const float* __restrict__ B, const float* __restrict__ att,
    float* __restrict__ hp)
{
    int idx = blockIdx.x * 256 + threadIdx.x;
    if (idx >= NH) return;
    int n = idx >> 7;
    int q = idx & 127;
    float s = 0.f;
    #pragma unroll
    for (int p = 0; p < 6; ++p) {
        int f = p * HID + q;
        int j = f % 6;
        int i = f / 6;
        s += att[(size_t)n * 6 + p] * B[(size_t)j * NH + (size_t)n * HID + i];
    }
    hp[idx] = s * (1.0f / 6.0f);
}

// ---------------------------------------------------------------------------
// FC layer: out[n,o] = leaky_relu( dot(in[n,:], W[o,:]) + bias[o] )
// W staged in LDS with pad-129 (bank = (o+k)%32, conflict-free).
// 2 rows per 256-thread block, grid-stride over row pairs.
// ---------------------------------------------------------------------------
__global__ __launch_bounds__(256) void fc_kernel(
    const float* __restrict__ in, const float* __restrict__ W,
    const float* __restrict__ bias, float* __restrict__ out)
{
    __shared__ float w[HID * 129];
    __shared__ float rb[2][HID];

    for (int i = threadIdx.x; i < HID * HID; i += 256) {
        int o = i >> 7, k = i & 127;
        w[o * 129 + k] = W[i];
    }
    __syncthreads();

    int rr = threadIdx.x >> 7;   // 0..1
    int o  = threadIdx.x & 127;
    float bo = bias[o];
    const float* wrow = w + o * 129;

    for (int pair = blockIdx.x; pair < N_NODES / 2; pair += gridDim.x) {
        int n = pair * 2 + rr;
        rb[rr][o] = in[(size_t)n * HID + o];
        __syncthreads();
        float a0 = 0.f, a1 = 0.f, a2 = 0.f, a3 = 0.f;
        #pragma unroll 8
        for (int k = 0; k < HID; k += 4) {
            a0 += rb[rr][k + 0] * wrow[k + 0];
            a1 += rb[rr][k + 1] * wrow[k + 1];
            a2 += rb[rr][k + 2] * wrow[k + 2];
            a3 += rb[rr][k + 3] * wrow[k + 3];
        }
        float acc = bo + ((a0 + a1) + (a2 + a3));
        acc = acc > 0.f ? acc : 0.01f * acc;
        out[(size_t)n * HID + o] = acc;
        __syncthreads();
    }
}

// ---------------------------------------------------------------------------
extern "C" void kernel_launch(void* const* d_in, const int* in_sizes, int n_in,
                              void* d_out, int out_size, void* d_ws, size_t ws_size,
                              hipStream_t stream)
{
    const float* X  = (const float*)d_in[0];
    const float* a  = (const float*)d_in[1];
    const float* W1 = (const float*)d_in[2];
    const float* b1 = (const float*)d_in[3];
    const float* W2 = (const float*)d_in[4];
    const float* b2 = (const float*)d_in[5];
    const int*   A_rows  = (const int*)d_in[6];
    const int*   A_cols  = (const int*)d_in[7];
    const float* A_vals  = (const float*)d_in[8];
    const int*   P1_rows = (const int*)d_in[9];
    const int*   P1_cols = (const int*)d_in[10];
    const float* P1_vals = (const float*)d_in[11];
    const int*   P2_rows = (const int*)d_in[12];
    const int*   P2_cols = (const int*)d_in[13];
    const float* P2_vals = (const float*)d_in[14];
    const int*   P3_rows = (const int*)d_in[15];
    const int*   P3_cols = (const int*)d_in[16];
    const float* P3_vals = (const float*)d_in[17];
    // d_in[18..20] = Psct (unused: withgres=False)

    float* ws  = (float*)d_ws;
    float* B   = ws;                       // 6 * NH  branch buffers
    float* att = ws + (size_t)6 * NH;      // 6 * N
    float* hp  = att + (size_t)6 * N_NODES;// NH
    float* mid = hp + NH;                  // NH

    // zero the 6 scatter-add targets
    hipMemsetAsync(B, 0, (size_t)6 * NH * sizeof(float), stream);

    dim3 blk(256);
    const int spmm_blocks = (NE * 32) / 256;  // 200000

    spmm_kernel<<<spmm_blocks, blk, 0, stream>>>(A_rows, A_cols, A_vals, X,          B + 0 * (size_t)NH);
    spmm_kernel<<<spmm_blocks, blk, 0, stream>>>(A_rows, A_cols, A_vals, B + 0 * (size_t)NH, B + 1 * (size_t)NH);
    spmm_kernel<<<spmm_blocks, blk, 0, stream>>>(A_rows, A_cols, A_vals, B + 1 * (size_t)NH, B + 2 * (size_t)NH);
    spmm_kernel<<<spmm_blocks, blk, 0, stream>>>(P1_rows, P1_cols, P1_vals, X,        B + 3 * (size_t)NH);
    spmm_kernel<<<spmm_blocks, blk, 0, stream>>>(P2_rows, P2_cols, P2_vals, X,        B + 4 * (size_t)NH);
    spmm_kernel<<<spmm_blocks, blk, 0, stream>>>(P3_rows, P3_cols, P3_vals, X,        B + 5 * (size_t)NH);

    abs_kernel<<<(3 * NH / 4 + 255) / 256, blk, 0, stream>>>(B + (size_t)3 * NH, 3 * NH / 4);

    attn_kernel<<<(N_NODES + 3) / 4, blk, 0, stream>>>(X, B, a, att);

    hprime_kernel<<<(NH + 255) / 256, blk, 0, stream>>>(B, att, hp);

    fc_kernel<<<512, blk, 0, stream>>>(hp,  W1, b1, mid);
    fc_kernel<<<512, blk, 0, stream>>>(mid, W2, b2, (float*)d_out);
}

// Round 2
// 2193.022 us; speedup vs baseline: 7.4433x; 7.4433x over previous
//
#include <hip/hip_runtime.h>

#define N_NODES 50000
#define HID 128
#define NE 1600000
#define NH (N_NODES * HID)   // 6,400,000 floats per [N,HID] buffer

// ===========================================================================
// Counting-sort COO -> CSR (per operator)
// ===========================================================================

// histogram: cnt[rows[e]]++  (fire-and-forget int atomics on 50K counters)
__global__ __launch_bounds__(256) void hist_kernel(
    const int* __restrict__ rows, int* __restrict__ cnt)
{
    int e = blockIdx.x * 256 + threadIdx.x;
    if (e < NE) atomicAdd(&cnt[rows[e]], 1);
}

// single-block exclusive scan of cnt[0..N) -> rowptr[0..N], and convert
// cnt in place into running offsets (offs) for the scatter pass.
__global__ __launch_bounds__(1024) void scan_kernel(
    int* __restrict__ cnt, int* __restrict__ rowptr)
{
    __shared__ int part[1024];
    const int t  = threadIdx.x;
    const int CH = (N_NODES + 1023) / 1024;  // 49
    const int base = t * CH;

    int s = 0;
    for (int i = 0; i < CH; ++i) {
        int idx = base + i;
        if (idx < N_NODES) s += cnt[idx];
    }
    part[t] = s;
    __syncthreads();
    // Hillis-Steele inclusive scan over 1024 partials
    for (int off = 1; off < 1024; off <<= 1) {
        int v = (t >= off) ? part[t - off] : 0;
        __syncthreads();
        part[t] += v;
        __syncthreads();
    }
    int run = (t == 0) ? 0 : part[t - 1];
    for (int i = 0; i < CH; ++i) {
        int idx = base + i;
        if (idx < N_NODES) {
            int c = cnt[idx];
            rowptr[idx] = run;
            cnt[idx]    = run;   // becomes the scatter offset array
            run += c;
        }
    }
    if (t == 1023) rowptr[N_NODES] = part[1023];
}

// scatter edges into row-sorted order as (col, val) int2 pairs
__global__ __launch_bounds__(256) void scatter_kernel(
    const int* __restrict__ rows, const int* __restrict__ cols,
    const float* __restrict__ vals, int* __restrict__ offs,
    int2* __restrict__ pairs)
{
    int e = blockIdx.x * 256 + threadIdx.x;
    if (e >= NE) return;
    int pos = atomicAdd(&offs[rows[e]], 1);
    pairs[pos] = make_int2(cols[e], __float_as_int(vals[e]));
}

// ===========================================================================
// CSR SpMM (gather form, no atomics): y[r,:] = sum_e val_e * x[col_e,:]
// 32 lanes per row, one float4 of columns per lane; 2-way unrolled edge loop.
// ABS fuses the |.| epilogue for the P branches.
// ===========================================================================
template <bool ABS>
__global__ __launch_bounds__(256) void csr_spmm_kernel(
    const int* __restrict__ rowptr, const int2* __restrict__ pairs,
    const float* __restrict__ x, float* __restrict__ y)
{
    int t   = blockIdx.x * 256 + threadIdx.x;
    int r   = t >> 5;
    int sub = t & 31;
    if (r >= N_NODES) return;

    const float4* x4 = (const float4*)x;
    int start = rowptr[r], end = rowptr[r + 1];

    float4 a0 = {0.f, 0.f, 0.f, 0.f};
    float4 a1 = {0.f, 0.f, 0.f, 0.f};
    int e = start;
    for (; e + 1 < end; e += 2) {
        int2 p0 = pairs[e];
        int2 p1 = pairs[e + 1];
        float4 x0 = x4[(size_t)p0.x * 32 + sub];
        float4 x1 = x4[(size_t)p1.x * 32 + sub];
        float v0 = __int_as_float(p0.y);
        float v1 = __int_as_float(p1.y);
        a0.x += v0 * x0.x; a0.y += v0 * x0.y; a0.z += v0 * x0.z; a0.w += v0 * x0.w;
        a1.x += v1 * x1.x; a1.y += v1 * x1.y; a1.z += v1 * x1.z; a1.w += v1 * x1.w;
    }
    if (e < end) {
        int2 p0 = pairs[e];
        float4 x0 = x4[(size_t)p0.x * 32 + sub];
        float v0 = __int_as_float(p0.y);
        a0.x += v0 * x0.x; a0.y += v0 * x0.y; a0.z += v0 * x0.z; a0.w += v0 * x0.w;
    }
    float4 acc;
    acc.x = a0.x + a1.x; acc.y = a0.y + a1.y;
    acc.z = a0.z + a1.z; acc.w = a0.w + a1.w;
    if (ABS) {
        acc.x = fabsf(acc.x); acc.y = fabsf(acc.y);
        acc.z = fabsf(acc.z); acc.w = fabsf(acc.w);
    }
    ((float4*)(y + (size_t)r * HID))[sub] = acc;
}

// ===========================================================================
// Attention: e[n,b] = dot(relu(pair_b[n]), a); att = softmax over b (6)
// pair_b[n]: n < N/2 -> X + n*256 (branch-independent);
//            n >= N/2 -> B_b + (2n-N)*128 (two contiguous rows).
// One wave per node, float4 per lane.
// ===========================================================================
__global__ __launch_bounds__(256) void attn_kernel(
    const float* __restrict__ X, const float* __restrict__ B,
    const float* __restrict__ a, float* __restrict__ att)
{
    int wid  = (blockIdx.x * 256 + threadIdx.x) >> 6;
    int lane = threadIdx.x & 63;
    if (wid >= N_NODES) return;

    const float4 av = ((const float4*)a)[lane];
    float e[6];

    if (wid < N_NODES / 2) {
        const float4 p = ((const float4*)(X + (size_t)wid * 256))[lane];
        float s = fmaxf(p.x, 0.f) * av.x + fmaxf(p.y, 0.f) * av.y +
                  fmaxf(p.z, 0.f) * av.z + fmaxf(p.w, 0.f) * av.w;
        #pragma unroll
        for (int m = 1; m < 64; m <<= 1) s += __shfl_xor(s, m);
        #pragma unroll
        for (int b = 0; b < 6; ++b) e[b] = s;
    } else {
        int m = 2 * wid - N_NODES;
        #pragma unroll
        for (int b = 0; b < 6; ++b) {
            const float4 p =
                ((const float4*)(B + (size_t)b * NH + (size_t)m * HID))[lane];
            float s = fmaxf(p.x, 0.f) * av.x + fmaxf(p.y, 0.f) * av.y +
                      fmaxf(p.z, 0.f) * av.z + fmaxf(p.w, 0.f) * av.w;
            #pragma unroll
            for (int k = 1; k < 64; k <<= 1) s += __shfl_xor(s, k);
            e[b] = s;
        }
    }

    if (lane == 0) {
        float mx = e[0];
        #pragma unroll
        for (int b = 1; b < 6; ++b) mx = fmaxf(mx, e[b]);
        float ex[6], sum = 0.f;
        #pragma unroll
        for (int b = 0; b < 6; ++b) { ex[b] = expf(e[b] - mx); sum += ex[b]; }
        float inv = 1.f / sum;
        #pragma unroll
        for (int b = 0; b < 6; ++b) att[(size_t)wid * 6 + b] = ex[b] * inv;
    }
}

// ===========================================================================
// h_prime[n,q] = (1/6) * sum_p att[n,p] * B_{(p*128+q)%6}[n, (p*128+q)/6]
// ===========================================================================
__global__ __launch_bounds__(256) void hprime_kernel(
    const float* __restrict__ B, const float* __restrict__ att,
    float* __restrict__ hp)
{
    int idx = blockIdx.x * 256 + threadIdx.x;
    if (idx >= NH) return;
    int n = idx >> 7;
    int q = idx & 127;
    float s = 0.f;
    #pragma unroll
    for (int p = 0; p < 6; ++p) {
        int f = p * HID + q;
        int j = f % 6;
        int i = f / 6;
        s += att[(size_t)n * 6 + p] * B[(size_t)j * NH + (size_t)n * HID + i];
    }
    hp[idx] = s * (1.0f / 6.0f);
}

// ===========================================================================
// FC layer (in-place safe): out[n,o] = leaky_relu(dot(in[n,:], W[o,:]) + b[o])
// ===========================================================================
__global__ __launch_bounds__(256) void fc_kernel(
    const float* __restrict__ in, const float* __restrict__ W,
    const float* __restrict__ bias, float* __restrict__ out)
{
    __shared__ float w[HID * 129];
    __shared__ float rb[2][HID];

    for (int i = threadIdx.x; i < HID * HID; i += 256) {
        int o = i >> 7, k = i & 127;
        w[o * 129 + k] = W[i];
    }
    __syncthreads();

    int rr = threadIdx.x >> 7;   // 0..1
    int o  = threadIdx.x & 127;
    float bo = bias[o];
    const float* wrow = w + o * 129;

    for (int pair = blockIdx.x; pair < N_NODES / 2; pair += gridDim.x) {
        int n = pair * 2 + rr;
        rb[rr][o] = in[(size_t)n * HID + o];
        __syncthreads();
        float a0 = 0.f, a1 = 0.f, a2 = 0.f, a3 = 0.f;
        #pragma unroll 8
        for (int k = 0; k < HID; k += 4) {
            a0 += rb[rr][k + 0] * wrow[k + 0];
            a1 += rb[rr][k + 1] * wrow[k + 1];
            a2 += rb[rr][k + 2] * wrow[k + 2];
            a3 += rb[rr][k + 3] * wrow[k + 3];
        }
        float acc = bo + ((a0 + a1) + (a2 + a3));
        acc = acc > 0.f ? acc : 0.01f * acc;
        out[(size_t)n * HID + o] = acc;
        __syncthreads();
    }
}

// ===========================================================================
extern "C" void kernel_launch(void* const* d_in, const int* in_sizes, int n_in,
                              void* d_out, int out_size, void* d_ws, size_t ws_size,
                              hipStream_t stream)
{
    const float* X  = (const float*)d_in[0];
    const float* a  = (const float*)d_in[1];
    const float* W1 = (const float*)d_in[2];
    const float* b1 = (const float*)d_in[3];
    const float* W2 = (const float*)d_in[4];
    const float* b2 = (const float*)d_in[5];
    const int*   A_rows  = (const int*)d_in[6];
    const int*   A_cols  = (const int*)d_in[7];
    const float* A_vals  = (const float*)d_in[8];
    const int*   P_rows[3] = { (const int*)d_in[9],  (const int*)d_in[12], (const int*)d_in[15] };
    const int*   P_cols[3] = { (const int*)d_in[10], (const int*)d_in[13], (const int*)d_in[16] };
    const float* P_vals[3] = { (const float*)d_in[11], (const float*)d_in[14], (const float*)d_in[17] };
    // d_in[18..20] = Psct (unused: withgres=False)

    // ---- workspace layout (4-byte units) ----
    float* ws = (float*)d_ws;
    float* B    = ws;                                  // 6*NH
    float* att  = B + (size_t)6 * NH;                  // 6*N
    int*   Aptr = (int*)(att + (size_t)6 * N_NODES);   // N+1 (+1 pad, keeps int2 8B-aligned)
    int2*  Apr  = (int2*)(Aptr + N_NODES + 2);         // NE int2
    int*   Pptr = (int*)(Apr + NE);                    // N+1 (+1 pad)
    int2*  Ppr  = (int2*)(Pptr + N_NODES + 2);         // NE int2
    int*   cnt  = (int*)(Ppr + NE);                    // N (hist -> offs)

    float* hp = (float*)d_out;   // hprime + both FCs run in-place in d_out

    dim3 blk(256);
    const int eg = (NE + 255) / 256;            // 6250 blocks over edges
    const int rg = (N_NODES * 32 + 255) / 256;  // 6250 blocks over rows (32 lanes/row)

    // ---- sort A, run 3 chained hops ----
    hipMemsetAsync(cnt, 0, N_NODES * sizeof(int), stream);
    hist_kernel<<<eg, blk, 0, stream>>>(A_rows, cnt);
    scan_kernel<<<1, 1024, 0, stream>>>(cnt, Aptr);
    scatter_kernel<<<eg, blk, 0, stream>>>(A_rows, A_cols, A_vals, cnt, Apr);

    csr_spmm_kernel<false><<<rg, blk, 0, stream>>>(Aptr, Apr, X,               B + 0 * (size_t)NH);
    csr_spmm_kernel<false><<<rg, blk, 0, stream>>>(Aptr, Apr, B + 0 * (size_t)NH, B + 1 * (size_t)NH);
    csr_spmm_kernel<false><<<rg, blk, 0, stream>>>(Aptr, Apr, B + 1 * (size_t)NH, B + 2 * (size_t)NH);

    // ---- P1..P3: sort into shared CSR buffer, spmm with fused abs ----
    for (int i = 0; i < 3; ++i) {
        hipMemsetAsync(cnt, 0, N_NODES * sizeof(int), stream);
        hist_kernel<<<eg, blk, 0, stream>>>(P_rows[i], cnt);
        scan_kernel<<<1, 1024, 0, stream>>>(cnt, Pptr);
        scatter_kernel<<<eg, blk, 0, stream>>>(P_rows[i], P_cols[i], P_vals[i], cnt, Ppr);
        csr_spmm_kernel<true><<<rg, blk, 0, stream>>>(Pptr, Ppr, X, B + (size_t)(3 + i) * NH);
    }

    // ---- attention, mix, FCs ----
    attn_kernel<<<(N_NODES + 3) / 4, blk, 0, stream>>>(X, B, a, att);
    hprime_kernel<<<(NH + 255) / 256, blk, 0, stream>>>(B, att, hp);
    fc_kernel<<<512, blk, 0, stream>>>(hp, W1, b1, hp);
    fc_kernel<<<512, blk, 0, stream>>>(hp, W2, b2, (float*)d_out);
}

// Round 3
// 1634.137 us; speedup vs baseline: 9.9890x; 1.3420x over previous
//
#include <hip/hip_runtime.h>

#define N_NODES 50000
#define HID 128
#define NE 1600000
#define NH (N_NODES * HID)   // 6,400,000 floats per [N,HID] buffer
#define NBLK 196             // ceil(N_NODES / 256)

// ===========================================================================
// Counting-sort COO -> CSR, batched across the 4 operators (A, P1, P2, P3)
// ===========================================================================

// histogram for all 4 operators: cnt[o*N + rows_o[e]]++   grid = (6250, 4)
__global__ __launch_bounds__(256) void hist4_kernel(
    const int* __restrict__ r0, const int* __restrict__ r1,
    const int* __restrict__ r2, const int* __restrict__ r3,
    int* __restrict__ cnt)
{
    int o = blockIdx.y;
    const int* rows = o == 0 ? r0 : o == 1 ? r1 : o == 2 ? r2 : r3;
    int e = blockIdx.x * 256 + threadIdx.x;
    if (e < NE) atomicAdd(&cnt[o * N_NODES + rows[e]], 1);
}

// per-block partial sums: bsum[o*NBLK + b] = sum of cnt block b   grid=(196,4)
__global__ __launch_bounds__(256) void partial_kernel(
    const int* __restrict__ cnt, int* __restrict__ bsum)
{
    __shared__ int red[256];
    int o = blockIdx.y, b = blockIdx.x, t = threadIdx.x;
    int idx = b * 256 + t;
    red[t] = (idx < N_NODES) ? cnt[o * N_NODES + idx] : 0;
    __syncthreads();
    #pragma unroll
    for (int s = 128; s > 0; s >>= 1) {
        if (t < s) red[t] += red[t + s];
        __syncthreads();
    }
    if (t == 0) bsum[o * NBLK + b] = red[0];
}

// one block: segmented exclusive scan of the 4*196 block sums (in place);
// also writes rowptr[N] = NE for each operator (edge count is constant).
__global__ __launch_bounds__(1024) void scanb_kernel(
    int* __restrict__ bsum,
    int* __restrict__ ptr0, int* __restrict__ ptr1,
    int* __restrict__ ptr2, int* __restrict__ ptr3)
{
    __shared__ int sh[4 * NBLK];
    int t = threadIdx.x;
    if (t < 4 * NBLK) sh[t] = bsum[t];
    __syncthreads();
    int seg = t / NBLK;
    for (int off = 1; off < NBLK; off <<= 1) {
        int v = 0;
        if (t < 4 * NBLK && t >= off && (t - off) / NBLK == seg) v = sh[t - off];
        __syncthreads();
        if (t < 4 * NBLK) sh[t] += v;
        __syncthreads();
    }
    if (t < 4 * NBLK) bsum[t] = (t % NBLK == 0) ? 0 : sh[t - 1];
    if (t == 0) ptr0[N_NODES] = NE;
    if (t == 1) ptr1[N_NODES] = NE;
    if (t == 2) ptr2[N_NODES] = NE;
    if (t == 3) ptr3[N_NODES] = NE;
}

// per-block local exclusive scan + block offset -> rowptr and scatter offsets
// (cnt is overwritten with the running offsets)                  grid=(196,4)
__global__ __launch_bounds__(256) void localscan_kernel(
    int* __restrict__ cnt, const int* __restrict__ bsum,
    int* __restrict__ ptr0, int* __restrict__ ptr1,
    int* __restrict__ ptr2, int* __restrict__ ptr3)
{
    __shared__ int sh[256];
    int o = blockIdx.y, b = blockIdx.x, t = threadIdx.x;
    int idx = b * 256 + t;
    sh[t] = (idx < N_NODES) ? cnt[o * N_NODES + idx] : 0;
    __syncthreads();
    #pragma unroll
    for (int off = 1; off < 256; off <<= 1) {
        int v = (t >= off) ? sh[t - off] : 0;
        __syncthreads();
        sh[t] += v;
        __syncthreads();
    }
    int exc = (t == 0) ? 0 : sh[t - 1];
    int off = bsum[o * NBLK + b] + exc;
    if (idx < N_NODES) {
        int* ptr = o == 0 ? ptr0 : o == 1 ? ptr1 : o == 2 ? ptr2 : ptr3;
        ptr[idx] = off;
        cnt[o * N_NODES + idx] = off;
    }
}

// scatter edges into row-sorted order as (col, val) int2 pairs
__global__ __launch_bounds__(256) void scatter_kernel(
    const int* __restrict__ rows, const int* __restrict__ cols,
    const float* __restrict__ vals, int* __restrict__ offs,
    int2* __restrict__ pairs)
{
    int e = blockIdx.x * 256 + threadIdx.x;
    if (e >= NE) return;
    int pos = atomicAdd(&offs[rows[e]], 1);
    pairs[pos] = make_int2(cols[e], __float_as_int(vals[e]));
}

// ===========================================================================
// CSR SpMM (gather form, no atomics): y[r,:] = sum_e val_e * x[col_e,:]
// 32 lanes per row, one float4 of columns per lane; 4-way unrolled edge loop
// for memory-level parallelism. ABS fuses |.| for the P branches.
// ===========================================================================
template <bool ABS>
__global__ __launch_bounds__(256) void csr_spmm_kernel(
    const int* __restrict__ rowptr, const int2* __restrict__ pairs,
    const float* __restrict__ x, float* __restrict__ y)
{
    int t   = blockIdx.x * 256 + threadIdx.x;
    int r   = t >> 5;
    int sub = t & 31;
    if (r >= N_NODES) return;

    const float4* x4 = (const float4*)x;
    int start = rowptr[r], end = rowptr[r + 1];

    float4 a0 = {0.f, 0.f, 0.f, 0.f};
    float4 a1 = {0.f, 0.f, 0.f, 0.f};
    float4 a2 = {0.f, 0.f, 0.f, 0.f};
    float4 a3 = {0.f, 0.f, 0.f, 0.f};
    int e = start;
    for (; e + 3 < end; e += 4) {
        int2 p0 = pairs[e];
        int2 p1 = pairs[e + 1];
        int2 p2 = pairs[e + 2];
        int2 p3 = pairs[e + 3];
        float4 x0 = x4[(size_t)p0.x * 32 + sub];
        float4 x1 = x4[(size_t)p1.x * 32 + sub];
        float4 x2 = x4[(size_t)p2.x * 32 + sub];
        float4 x3 = x4[(size_t)p3.x * 32 + sub];
        float v0 = __int_as_float(p0.y);
        float v1 = __int_as_float(p1.y);
        float v2 = __int_as_float(p2.y);
        float v3 = __int_as_float(p3.y);
        a0.x += v0 * x0.x; a0.y += v0 * x0.y; a0.z += v0 * x0.z; a0.w += v0 * x0.w;
        a1.x += v1 * x1.x; a1.y += v1 * x1.y; a1.z += v1 * x1.z; a1.w += v1 * x1.w;
        a2.x += v2 * x2.x; a2.y += v2 * x2.y; a2.z += v2 * x2.z; a2.w += v2 * x2.w;
        a3.x += v3 * x3.x; a3.y += v3 * x3.y; a3.z += v3 * x3.z; a3.w += v3 * x3.w;
    }
    for (; e < end; ++e) {
        int2 p0 = pairs[e];
        float4 x0 = x4[(size_t)p0.x * 32 + sub];
        float v0 = __int_as_float(p0.y);
        a0.x += v0 * x0.x; a0.y += v0 * x0.y; a0.z += v0 * x0.z; a0.w += v0 * x0.w;
    }
    float4 acc;
    acc.x = (a0.x + a1.x) + (a2.x + a3.x);
    acc.y = (a0.y + a1.y) + (a2.y + a3.y);
    acc.z = (a0.z + a1.z) + (a2.z + a3.z);
    acc.w = (a0.w + a1.w) + (a2.w + a3.w);
    if (ABS) {
        acc.x = fabsf(acc.x); acc.y = fabsf(acc.y);
        acc.z = fabsf(acc.z); acc.w = fabsf(acc.w);
    }
    ((float4*)(y + (size_t)r * HID))[sub] = acc;
}

// ===========================================================================
// Attention: e[n,b] = dot(relu(pair_b[n]), a); att = softmax over b (6)
// ===========================================================================
__global__ __launch_bounds__(256) void attn_kernel(
    const float* __restrict__ X, const float* __restrict__ B,
    const float* __restrict__ a, float* __restrict__ att)
{
    int wid  = (blockIdx.x * 256 + threadIdx.x) >> 6;
    int lane = threadIdx.x & 63;
    if (wid >= N_NODES) return;

    const float4 av = ((const float4*)a)[lane];
    float e[6];

    if (wid < N_NODES / 2) {
        const float4 p = ((const float4*)(X + (size_t)wid * 256))[lane];
        float s = fmaxf(p.x, 0.f) * av.x + fmaxf(p.y, 0.f) * av.y +
                  fmaxf(p.z, 0.f) * av.z + fmaxf(p.w, 0.f) * av.w;
        #pragma unroll
        for (int m = 1; m < 64; m <<= 1) s += __shfl_xor(s, m);
        #pragma unroll
        for (int b = 0; b < 6; ++b) e[b] = s;
    } else {
        int m = 2 * wid - N_NODES;
        #pragma unroll
        for (int b = 0; b < 6; ++b) {
            const float4 p =
                ((const float4*)(B + (size_t)b * NH + (size_t)m * HID))[lane];
            float s = fmaxf(p.x, 0.f) * av.x + fmaxf(p.y, 0.f) * av.y +
                      fmaxf(p.z, 0.f) * av.z + fmaxf(p.w, 0.f) * av.w;
            #pragma unroll
            for (int k = 1; k < 64; k <<= 1) s += __shfl_xor(s, k);
            e[b] = s;
        }
    }

    if (lane == 0) {
        float mx = e[0];
        #pragma unroll
        for (int b = 1; b < 6; ++b) mx = fmaxf(mx, e[b]);
        float ex[6], sum = 0.f;
        #pragma unroll
        for (int b = 0; b < 6; ++b) { ex[b] = expf(e[b] - mx); sum += ex[b]; }
        float inv = 1.f / sum;
        #pragma unroll
        for (int b = 0; b < 6; ++b) att[(size_t)wid * 6 + b] = ex[b] * inv;
    }
}

// ===========================================================================
// h_prime[n,q] = (1/6) * sum_p att[n,p] * B_{(p*128+q)%6}[n, (p*128+q)/6]
// ===========================================================================
__global__ __launch_bounds__(256) void hprime_kernel(
    const float* __restrict__ B, const float* __restrict__ att,
    float* __restrict__ hp)
{
    int idx = blockIdx.x * 256 + threadIdx.x;
    if (idx >= NH) return;
    int n = idx >> 7;
    int q = idx & 127;
    float s = 0.f;
    #pragma unroll
    for (int p = 0; p < 6; ++p) {
        int f = p * HID + q;
        int j = f % 6;
        int i = f / 6;
        s += att[(size_t)n * 6 + p] * B[(size_t)j * NH + (size_t)n * HID + i];
    }
    hp[idx] = s * (1.0f / 6.0f);
}

// ===========================================================================
// FC layer (in-place safe): out[n,o] = leaky_relu(dot(in[n,:], W[o,:]) + b[o])
// ===========================================================================
__global__ __launch_bounds__(256) void fc_kernel(
    const float* __restrict__ in, const float* __restrict__ W,
    const float* __restrict__ bias, float* __restrict__ out)
{
    __shared__ float w[HID * 129];
    __shared__ float rb[2][HID];

    for (int i = threadIdx.x; i < HID * HID; i += 256) {
        int o = i >> 7, k = i & 127;
        w[o * 129 + k] = W[i];
    }
    __syncthreads();

    int rr = threadIdx.x >> 7;   // 0..1
    int o  = threadIdx.x & 127;
    float bo = bias[o];
    const float* wrow = w + o * 129;

    for (int pair = blockIdx.x; pair < N_NODES / 2; pair += gridDim.x) {
        int n = pair * 2 + rr;
        rb[rr][o] = in[(size_t)n * HID + o];
        __syncthreads();
        float a0 = 0.f, a1 = 0.f, a2 = 0.f, a3 = 0.f;
        #pragma unroll 8
        for (int k = 0; k < HID; k += 4) {
            a0 += rb[rr][k + 0] * wrow[k + 0];
            a1 += rb[rr][k + 1] * wrow[k + 1];
            a2 += rb[rr][k + 2] * wrow[k + 2];
            a3 += rb[rr][k + 3] * wrow[k + 3];
        }
        float acc = bo + ((a0 + a1) + (a2 + a3));
        acc = acc > 0.f ? acc : 0.01f * acc;
        out[(size_t)n * HID + o] = acc;
        __syncthreads();
    }
}

// ===========================================================================
extern "C" void kernel_launch(void* const* d_in, const int* in_sizes, int n_in,
                              void* d_out, int out_size, void* d_ws, size_t ws_size,
                              hipStream_t stream)
{
    const float* X  = (const float*)d_in[0];
    const float* a  = (const float*)d_in[1];
    const float* W1 = (const float*)d_in[2];
    const float* b1 = (const float*)d_in[3];
    const float* W2 = (const float*)d_in[4];
    const float* b2 = (const float*)d_in[5];
    const int*   A_rows  = (const int*)d_in[6];
    const int*   A_cols  = (const int*)d_in[7];
    const float* A_vals  = (const float*)d_in[8];
    const int*   P_rows[3] = { (const int*)d_in[9],  (const int*)d_in[12], (const int*)d_in[15] };
    const int*   P_cols[3] = { (const int*)d_in[10], (const int*)d_in[13], (const int*)d_in[16] };
    const float* P_vals[3] = { (const float*)d_in[11], (const float*)d_in[14], (const float*)d_in[17] };
    // d_in[18..20] = Psct (unused: withgres=False)

    // ---- workspace layout (4-byte units) ----
    float* ws = (float*)d_ws;
    float* B    = ws;                                   // 6*NH
    float* att  = B + (size_t)6 * NH;                   // 6*N
    int*   ptr0 = (int*)(att + (size_t)6 * N_NODES);    // N+2 each (pad for int2 align)
    int*   ptr1 = ptr0 + N_NODES + 2;
    int*   ptr2 = ptr1 + N_NODES + 2;
    int*   ptr3 = ptr2 + N_NODES + 2;
    int*   cnt  = ptr3 + N_NODES + 2;                   // 4*N (hist -> offsets)
    int*   bsum = cnt + 4 * N_NODES;                    // 4*NBLK (pad 1024)
    int2*  Apr  = (int2*)(bsum + 1024);                 // NE int2
    int2*  Ppr  = Apr + NE;                             // NE int2 (shared by P1..P3)

    float* hp = (float*)d_out;   // hprime + both FCs run in-place in d_out

    dim3 blk(256);
    const int eg = (NE + 255) / 256;            // 6250
    const int rg = (N_NODES * 32 + 255) / 256;  // 6250

    // ---- batched counting sort: hist + hierarchical scan ----
    hipMemsetAsync(cnt, 0, 4 * N_NODES * sizeof(int), stream);
    hist4_kernel<<<dim3(eg, 4), blk, 0, stream>>>(A_rows, P_rows[0], P_rows[1], P_rows[2], cnt);
    partial_kernel<<<dim3(NBLK, 4), blk, 0, stream>>>(cnt, bsum);
    scanb_kernel<<<1, 1024, 0, stream>>>(bsum, ptr0, ptr1, ptr2, ptr3);
    localscan_kernel<<<dim3(NBLK, 4), blk, 0, stream>>>(cnt, bsum, ptr0, ptr1, ptr2, ptr3);

    // ---- A: scatter + 3 chained hops ----
    scatter_kernel<<<eg, blk, 0, stream>>>(A_rows, A_cols, A_vals, cnt, Apr);
    csr_spmm_kernel<false><<<rg, blk, 0, stream>>>(ptr0, Apr, X,               B + 0 * (size_t)NH);
    csr_spmm_kernel<false><<<rg, blk, 0, stream>>>(ptr0, Apr, B + 0 * (size_t)NH, B + 1 * (size_t)NH);
    csr_spmm_kernel<false><<<rg, blk, 0, stream>>>(ptr0, Apr, B + 1 * (size_t)NH, B + 2 * (size_t)NH);

    // ---- P1..P3: scatter into shared pair buffer, spmm with fused abs ----
    int* pptrs[3] = { ptr1, ptr2, ptr3 };
    for (int i = 0; i < 3; ++i) {
        scatter_kernel<<<eg, blk, 0, stream>>>(P_rows[i], P_cols[i], P_vals[i],
                                               cnt + (size_t)(1 + i) * N_NODES, Ppr);
        csr_spmm_kernel<true><<<rg, blk, 0, stream>>>(pptrs[i], Ppr, X, B + (size_t)(3 + i) * NH);
    }

    // ---- attention, mix, FCs ----
    attn_kernel<<<(N_NODES + 3) / 4, blk, 0, stream>>>(X, B, a, att);
    hprime_kernel<<<(NH + 255) / 256, blk, 0, stream>>>(B, att, hp);
    fc_kernel<<<512, blk, 0, stream>>>(hp, W1, b1, hp);
    fc_kernel<<<512, blk, 0, stream>>>(hp, W2, b2, (float*)d_out);
}

// Round 4
// 1175.482 us; speedup vs baseline: 13.8866x; 1.3902x over previous
//
#include <hip/hip_runtime.h>

#define N_NODES 50000
#define HID 128
#define NE 1600000
#define NH (N_NODES * HID)      // 6,400,000 floats per [N,HID] buffer

#define EPB   4096              // edges per K1/K3 block
#define NBLK1 391               // ceil(NE / EPB)
#define NBUK  391               // ceil(N_NODES / 128) row buckets (128 rows each)
#define TBL   (NBUK * NBLK1)    // 152,881 scan table entries
#define SB    ((TBL + 255) / 256)  // 598 scan blocks

// ===========================================================================
// K1: per-block LDS histogram over 391 coarse buckets + per-edge rank.
// No global atomics.
// ===========================================================================
__global__ __launch_bounds__(256) void k1_hist(
    const int* __restrict__ rows, int* __restrict__ table,
    unsigned short* __restrict__ rank)
{
    __shared__ int h[NBUK];
    int b = blockIdx.x, t = threadIdx.x;
    for (int i = t; i < NBUK; i += 256) h[i] = 0;
    __syncthreads();
    int e0 = b * EPB;
    int e1 = min(e0 + EPB, NE);
    for (int e = e0 + t; e < e1; e += 256)
        rank[e] = (unsigned short)atomicAdd(&h[rows[e] >> 7], 1);
    __syncthreads();
    for (int i = t; i < NBUK; i += 256) table[i * NBLK1 + b] = h[i];
}

// ===========================================================================
// S1/S2/S3: hierarchical exclusive scan of table[TBL] (bucket-major)
// ===========================================================================
__global__ __launch_bounds__(256) void s1_partial(
    const int* __restrict__ table, int* __restrict__ part)
{
    __shared__ int red[256];
    int b = blockIdx.x, t = threadIdx.x;
    int idx = b * 256 + t;
    red[t] = (idx < TBL) ? table[idx] : 0;
    __syncthreads();
    #pragma unroll
    for (int s = 128; s > 0; s >>= 1) {
        if (t < s) red[t] += red[t + s];
        __syncthreads();
    }
    if (t == 0) part[b] = red[0];
}

__global__ __launch_bounds__(1024) void s2_scan(int* __restrict__ part)
{
    __shared__ int sh[1024];
    int t = threadIdx.x;
    sh[t] = (t < SB) ? part[t] : 0;
    __syncthreads();
    for (int off = 1; off < 1024; off <<= 1) {
        int v = (t >= off) ? sh[t - off] : 0;
        __syncthreads();
        sh[t] += v;
        __syncthreads();
    }
    if (t < SB) part[t] = (t == 0) ? 0 : sh[t - 1];
}

__global__ __launch_bounds__(256) void s3_add(
    int* __restrict__ table, const int* __restrict__ part)
{
    __shared__ int sh[256];
    int b = blockIdx.x, t = threadIdx.x;
    int idx = b * 256 + t;
    int v = (idx < TBL) ? table[idx] : 0;
    sh[t] = v;
    __syncthreads();
    #pragma unroll
    for (int off = 1; off < 256; off <<= 1) {
        int u = (t >= off) ? sh[t - off] : 0;
        __syncthreads();
        sh[t] += u;
        __syncthreads();
    }
    int excl = (t == 0) ? 0 : sh[t - 1];
    if (idx < TBL) table[idx] = part[b] + excl;
}

// ===========================================================================
// K3: atomic-free scatter into bucket-partitioned tmp.
// word0 = (row&127)<<16 | col  (col < 65536), word1 = val bits.
// ===========================================================================
__global__ __launch_bounds__(256) void k3_scatter(
    const int* __restrict__ rows, const int* __restrict__ cols,
    const float* __restrict__ vals, const unsigned short* __restrict__ rank,
    const int* __restrict__ table, int2* __restrict__ tmp)
{
    __shared__ int base[NBUK];
    int b = blockIdx.x, t = threadIdx.x;
    for (int i = t; i < NBUK; i += 256) base[i] = table[i * NBLK1 + b];
    __syncthreads();
    int e0 = b * EPB;
    int e1 = min(e0 + EPB, NE);
    for (int e = e0 + t; e < e1; e += 256) {
        int r = rows[e];
        int pos = base[r >> 7] + (int)rank[e];
        tmp[pos] = make_int2(((r & 127) << 16) | cols[e], __float_as_int(vals[e]));
    }
}

// ===========================================================================
// K4: per-bucket fine sort (128 rows) -> final CSR pairs + rowptr.
// LDS atomics only; writes confined to the bucket's 32KB window.
// ===========================================================================
__global__ __launch_bounds__(256) void k4_fine(
    const int* __restrict__ table, const int2* __restrict__ tmp,
    int2* __restrict__ pairs, int* __restrict__ rowptr)
{
    __shared__ int cnt[128];
    __shared__ int sh[256];
    __shared__ int nxt[128];
    int k = blockIdx.x, t = threadIdx.x;
    if (t < 128) cnt[t] = 0;
    __syncthreads();
    int base = table[k * NBLK1];
    int end  = (k == NBUK - 1) ? NE : table[(k + 1) * NBLK1];
    for (int e = base + t; e < end; e += 256)
        atomicAdd(&cnt[(tmp[e].x >> 16) & 127], 1);
    __syncthreads();
    sh[t] = (t < 128) ? cnt[t] : 0;
    __syncthreads();
    #pragma unroll
    for (int off = 1; off < 256; off <<= 1) {
        int v = (t >= off) ? sh[t - off] : 0;
        __syncthreads();
        sh[t] += v;
        __syncthreads();
    }
    if (t < 128) {
        int excl = (t == 0) ? 0 : sh[t - 1];
        nxt[t] = base + excl;
        int row = k * 128 + t;
        if (row < N_NODES) rowptr[row] = base + excl;
    }
    if (k == NBUK - 1 && t == 255) rowptr[N_NODES] = NE;
    __syncthreads();
    for (int e = base + t; e < end; e += 256) {
        int2 p = tmp[e];
        int pos = atomicAdd(&nxt[(p.x >> 16) & 127], 1);
        pairs[pos] = make_int2(p.x & 0xFFFF, p.y);
    }
}

// ===========================================================================
// CSR SpMM (gather form, no atomics): y[r,:] = sum_e val_e * x[col_e,:]
// 32 lanes per row, one float4 of columns per lane; 4-way unrolled.
// ===========================================================================
template <bool ABS>
__global__ __launch_bounds__(256) void csr_spmm_kernel(
    const int* __restrict__ rowptr, const int2* __restrict__ pairs,
    const float* __restrict__ x, float* __restrict__ y)
{
    int t   = blockIdx.x * 256 + threadIdx.x;
    int r   = t >> 5;
    int sub = t & 31;
    if (r >= N_NODES) return;

    const float4* x4 = (const float4*)x;
    int start = rowptr[r], end = rowptr[r + 1];

    float4 a0 = {0.f, 0.f, 0.f, 0.f};
    float4 a1 = {0.f, 0.f, 0.f, 0.f};
    float4 a2 = {0.f, 0.f, 0.f, 0.f};
    float4 a3 = {0.f, 0.f, 0.f, 0.f};
    int e = start;
    for (; e + 3 < end; e += 4) {
        int2 p0 = pairs[e];
        int2 p1 = pairs[e + 1];
        int2 p2 = pairs[e + 2];
        int2 p3 = pairs[e + 3];
        float4 x0 = x4[(size_t)p0.x * 32 + sub];
        float4 x1 = x4[(size_t)p1.x * 32 + sub];
        float4 x2 = x4[(size_t)p2.x * 32 + sub];
        float4 x3 = x4[(size_t)p3.x * 32 + sub];
        float v0 = __int_as_float(p0.y);
        float v1 = __int_as_float(p1.y);
        float v2 = __int_as_float(p2.y);
        float v3 = __int_as_float(p3.y);
        a0.x += v0 * x0.x; a0.y += v0 * x0.y; a0.z += v0 * x0.z; a0.w += v0 * x0.w;
        a1.x += v1 * x1.x; a1.y += v1 * x1.y; a1.z += v1 * x1.z; a1.w += v1 * x1.w;
        a2.x += v2 * x2.x; a2.y += v2 * x2.y; a2.z += v2 * x2.z; a2.w += v2 * x2.w;
        a3.x += v3 * x3.x; a3.y += v3 * x3.y; a3.z += v3 * x3.z; a3.w += v3 * x3.w;
    }
    for (; e < end; ++e) {
        int2 p0 = pairs[e];
        float4 x0 = x4[(size_t)p0.x * 32 + sub];
        float v0 = __int_as_float(p0.y);
        a0.x += v0 * x0.x; a0.y += v0 * x0.y; a0.z += v0 * x0.z; a0.w += v0 * x0.w;
    }
    float4 acc;
    acc.x = (a0.x + a1.x) + (a2.x + a3.x);
    acc.y = (a0.y + a1.y) + (a2.y + a3.y);
    acc.z = (a0.z + a1.z) + (a2.z + a3.z);
    acc.w = (a0.w + a1.w) + (a2.w + a3.w);
    if (ABS) {
        acc.x = fabsf(acc.x); acc.y = fabsf(acc.y);
        acc.z = fabsf(acc.z); acc.w = fabsf(acc.w);
    }
    ((float4*)(y + (size_t)r * HID))[sub] = acc;
}

// ===========================================================================
// Attention: e[n,b] = dot(relu(pair_b[n]), a); att = softmax over b (6)
// ===========================================================================
__global__ __launch_bounds__(256) void attn_kernel(
    const float* __restrict__ X, const float* __restrict__ B,
    const float* __restrict__ a, float* __restrict__ att)
{
    int wid  = (blockIdx.x * 256 + threadIdx.x) >> 6;
    int lane = threadIdx.x & 63;
    if (wid >= N_NODES) return;

    const float4 av = ((const float4*)a)[lane];
    float e[6];

    if (wid < N_NODES / 2) {
        const float4 p = ((const float4*)(X + (size_t)wid * 256))[lane];
        float s = fmaxf(p.x, 0.f) * av.x + fmaxf(p.y, 0.f) * av.y +
                  fmaxf(p.z, 0.f) * av.z + fmaxf(p.w, 0.f) * av.w;
        #pragma unroll
        for (int m = 1; m < 64; m <<= 1) s += __shfl_xor(s, m);
        #pragma unroll
        for (int b = 0; b < 6; ++b) e[b] = s;
    } else {
        int m = 2 * wid - N_NODES;
        #pragma unroll
        for (int b = 0; b < 6; ++b) {
            const float4 p =
                ((const float4*)(B + (size_t)b * NH + (size_t)m * HID))[lane];
            float s = fmaxf(p.x, 0.f) * av.x + fmaxf(p.y, 0.f) * av.y +
                      fmaxf(p.z, 0.f) * av.z + fmaxf(p.w, 0.f) * av.w;
            #pragma unroll
            for (int k = 1; k < 64; k <<= 1) s += __shfl_xor(s, k);
            e[b] = s;
        }
    }

    if (lane == 0) {
        float mx = e[0];
        #pragma unroll
        for (int b = 1; b < 6; ++b) mx = fmaxf(mx, e[b]);
        float ex[6], sum = 0.f;
        #pragma unroll
        for (int b = 0; b < 6; ++b) { ex[b] = expf(e[b] - mx); sum += ex[b]; }
        float inv = 1.f / sum;
        #pragma unroll
        for (int b = 0; b < 6; ++b) att[(size_t)wid * 6 + b] = ex[b] * inv;
    }
}

// ===========================================================================
// h_prime[n,q] = (1/6) * sum_p att[n,p] * B_{(p*128+q)%6}[n, (p*128+q)/6]
// ===========================================================================
__global__ __launch_bounds__(256) void hprime_kernel(
    const float* __restrict__ B, const float* __restrict__ att,
    float* __restrict__ hp)
{
    int idx = blockIdx.x * 256 + threadIdx.x;
    if (idx >= NH) return;
    int n = idx >> 7;
    int q = idx & 127;
    float s = 0.f;
    #pragma unroll
    for (int p = 0; p < 6; ++p) {
        int f = p * HID + q;
        int j = f % 6;
        int i = f / 6;
        s += att[(size_t)n * 6 + p] * B[(size_t)j * NH + (size_t)n * HID + i];
    }
    hp[idx] = s * (1.0f / 6.0f);
}

// ===========================================================================
// FC layer (in-place safe): out[n,o] = leaky_relu(dot(in[n,:], W[o,:]) + b[o])
// ===========================================================================
__global__ __launch_bounds__(256) void fc_kernel(
    const float* __restrict__ in, const float* __restrict__ W,
    const float* __restrict__ bias, float* __restrict__ out)
{
    __shared__ float w[HID * 129];
    __shared__ float rb[2][HID];

    for (int i = threadIdx.x; i < HID * HID; i += 256) {
        int o = i >> 7, k = i & 127;
        w[o * 129 + k] = W[i];
    }
    __syncthreads();

    int rr = threadIdx.x >> 7;   // 0..1
    int o  = threadIdx.x & 127;
    float bo = bias[o];
    const float* wrow = w + o * 129;

    for (int pair = blockIdx.x; pair < N_NODES / 2; pair += gridDim.x) {
        int n = pair * 2 + rr;
        rb[rr][o] = in[(size_t)n * HID + o];
        __syncthreads();
        float a0 = 0.f, a1 = 0.f, a2 = 0.f, a3 = 0.f;
        #pragma unroll 8
        for (int k = 0; k < HID; k += 4) {
            a0 += rb[rr][k + 0] * wrow[k + 0];
            a1 += rb[rr][k + 1] * wrow[k + 1];
            a2 += rb[rr][k + 2] * wrow[k + 2];
            a3 += rb[rr][k + 3] * wrow[k + 3];
        }
        float acc = bo + ((a0 + a1) + (a2 + a3));
        acc = acc > 0.f ? acc : 0.01f * acc;
        out[(size_t)n * HID + o] = acc;
        __syncthreads();
    }
}

// ===========================================================================
extern "C" void kernel_launch(void* const* d_in, const int* in_sizes, int n_in,
                              void* d_out, int out_size, void* d_ws, size_t ws_size,
                              hipStream_t stream)
{
    const float* X  = (const float*)d_in[0];
    const float* a  = (const float*)d_in[1];
    const float* W1 = (const float*)d_in[2];
    const float* b1 = (const float*)d_in[3];
    const float* W2 = (const float*)d_in[4];
    const float* b2 = (const float*)d_in[5];
    const int*   op_rows[4] = { (const int*)d_in[6],  (const int*)d_in[9],
                                (const int*)d_in[12], (const int*)d_in[15] };
    const int*   op_cols[4] = { (const int*)d_in[7],  (const int*)d_in[10],
                                (const int*)d_in[13], (const int*)d_in[16] };
    const float* op_vals[4] = { (const float*)d_in[8],  (const float*)d_in[11],
                                (const float*)d_in[14], (const float*)d_in[17] };
    // d_in[18..20] = Psct (unused: withgres=False)

    // ---- workspace layout (4-byte words, keep int2 buffers 8B-aligned) ----
    float* ws = (float*)d_ws;
    float* B     = ws;                                     // 6*NH
    float* att   = B + (size_t)6 * NH;                     // 6*N
    int*   ptr   = (int*)(att + (size_t)6 * N_NODES);      // N+2
    int*   table = ptr + N_NODES + 2;                      // TBL (pad to even)
    int*   part  = table + TBL + 1;                        // 1024
    unsigned short* brnk = (unsigned short*)(part + 1024); // NE ushort = NE/2 words
    int2*  tmp   = (int2*)((int*)brnk + NE / 2);           // NE int2
    int2*  pairs = tmp + NE;                               // NE int2 (shared by all ops)

    float* hp = (float*)d_out;   // hprime + both FCs run in-place in d_out

    dim3 blk(256);
    const int rg = (N_NODES * 32 + 255) / 256;  // 6250

    // sorts one operator into (pairs, ptr) — no global atomics anywhere
    auto sort_op = [&](int o) {
        k1_hist<<<NBLK1, blk, 0, stream>>>(op_rows[o], table, brnk);
        s1_partial<<<SB, blk, 0, stream>>>(table, part);
        s2_scan<<<1, 1024, 0, stream>>>(part);
        s3_add<<<SB, blk, 0, stream>>>(table, part);
        k3_scatter<<<NBLK1, blk, 0, stream>>>(op_rows[o], op_cols[o], op_vals[o],
                                              brnk, table, tmp);
        k4_fine<<<NBUK, blk, 0, stream>>>(table, tmp, pairs, ptr);
    };

    // ---- A: sort, then 3 chained hops (CSR dead afterwards -> P's reuse) ----
    sort_op(0);
    csr_spmm_kernel<false><<<rg, blk, 0, stream>>>(ptr, pairs, X,               B + 0 * (size_t)NH);
    csr_spmm_kernel<false><<<rg, blk, 0, stream>>>(ptr, pairs, B + 0 * (size_t)NH, B + 1 * (size_t)NH);
    csr_spmm_kernel<false><<<rg, blk, 0, stream>>>(ptr, pairs, B + 1 * (size_t)NH, B + 2 * (size_t)NH);

    // ---- P1..P3: sort (reusing buffers), spmm with fused abs ----
    for (int i = 0; i < 3; ++i) {
        sort_op(1 + i);
        csr_spmm_kernel<true><<<rg, blk, 0, stream>>>(ptr, pairs, X, B + (size_t)(3 + i) * NH);
    }

    // ---- attention, mix, FCs ----
    attn_kernel<<<(N_NODES + 3) / 4, blk, 0, stream>>>(X, B, a, att);
    hprime_kernel<<<(NH + 255) / 256, blk, 0, stream>>>(B, att, hp);
    fc_kernel<<<512, blk, 0, stream>>>(hp, W1, b1, hp);
    fc_kernel<<<512, blk, 0, stream>>>(hp, W2, b2, (float*)d_out);
}